// Round 2
// baseline (323.970 us; speedup 1.0000x reference)
//
#include <hip/hip_runtime.h>

#define NSTEP 365
#define NGRID 50000
#define PRECS_F 1e-5f
#define CHUNK 16

#if defined(__has_builtin)
#  if __has_builtin(__builtin_amdgcn_exp2f) && __has_builtin(__builtin_amdgcn_logf)
#    define FAST_EXP2(x) __builtin_amdgcn_exp2f(x)
#    define FAST_LOG2(x) __builtin_amdgcn_logf(x)
#  endif
#endif
#ifndef FAST_EXP2
#  define FAST_EXP2(x) exp2f(x)
#  define FAST_LOG2(x) log2f(x)
#endif

__global__ __launch_bounds__(64) void hbv_kernel(const float* __restrict__ x,
                                                 const float* __restrict__ params,
                                                 float* __restrict__ out) {
    const int g = blockIdx.x * blockDim.x + threadIdx.x;
    if (g >= NGRID) return;

    // ---- scale parameters: p = lo + raw * (hi - lo) ----
    const float* pr = params + (size_t)g * 14;
    float r0 = pr[0], r1 = pr[1], r2 = pr[2], r3 = pr[3], r4 = pr[4], r5 = pr[5];
    float r6 = pr[6], r7 = pr[7], r8 = pr[8], r9 = pr[9], r10 = pr[10], r11 = pr[11];

    const float parBETA  = 1.0f   + r0  * 5.0f;
    const float parFC    = 50.0f  + r1  * 950.0f;
    const float parK0    = 0.05f  + r2  * 0.85f;
    const float parK1    = 0.01f  + r3  * 0.49f;
    const float parK2    = 0.001f + r4  * 0.199f;
    const float parLP    = 0.2f   + r5  * 0.8f;
    const float parPERC  =          r6  * 10.0f;
    const float parUZL   =          r7  * 100.0f;
    const float parTT    = -2.5f  + r8  * 5.0f;
    const float parCFMAX = 0.5f   + r9  * 9.5f;
    const float parCFR   =          r10 * 0.1f;
    const float parCWH   =          r11 * 0.2f;

    const float invFC     = 1.0f / parFC;
    const float invLPFC   = 1.0f / (parLP * parFC);
    const float cfr_cfmax = parCFR * parCFMAX;

    float SNOWPACK = 0.001f, MELTWATER = 0.001f, SM = 0.001f, SUZ = 0.001f, SLZ = 0.001f;

    const int nchunks = (NSTEP + CHUNK - 1) / CHUNK;  // 23

    float AP[CHUNK], AT[CHUNK], AE[CHUNK];
    float BP[CHUNK], BT[CHUNK], BE[CHUNK];

    auto load_chunk = [&](int cidx, float (&P)[CHUNK], float (&T)[CHUNK], float (&E)[CHUNK]) {
        const int tbase = cidx * CHUNK;
        #pragma unroll
        for (int j = 0; j < CHUNK; ++j) {
            int t = tbase + j;
            t = (t < NSTEP) ? t : (NSTEP - 1);           // clamp (tail chunk)
            const float* p = x + ((size_t)t * NGRID + g) * 3;
            P[j] = p[0];
            T[j] = p[1];
            E[j] = p[2];
        }
    };

    auto compute_chunk = [&](int cidx, const float (&P)[CHUNK], const float (&T)[CHUNK],
                             const float (&E)[CHUNK]) {
        const int t0 = cidx * CHUNK;
        #pragma unroll
        for (int j = 0; j < CHUNK; ++j) {
            const float PRECIP = P[j];
            const float Tt     = T[j];
            const float ETp    = E[j];

            float RAIN = (Tt >= parTT) ? PRECIP : 0.0f;
            float SNOW = PRECIP - RAIN;
            SNOWPACK += SNOW;
            float melt = fminf(fmaxf(parCFMAX * (Tt - parTT), 0.0f), SNOWPACK);
            MELTWATER += melt;
            SNOWPACK  -= melt;
            float refreeze = fminf(fmaxf(cfr_cfmax * (parTT - Tt), 0.0f), MELTWATER);
            SNOWPACK  += refreeze;
            MELTWATER -= refreeze;
            float tosoil = fmaxf(MELTWATER - parCWH * SNOWPACK, 0.0f);
            MELTWATER -= tosoil;

            float ratio = SM * invFC;                     // SM in (0, FC] -> ratio in (0, 1]
            float sw = FAST_EXP2(parBETA * FAST_LOG2(ratio));
            sw = fminf(fmaxf(sw, 0.0f), 1.0f);
            float recharge = (RAIN + tosoil) * sw;
            SM += RAIN + tosoil - recharge;
            float excess = fmaxf(SM - parFC, 0.0f);
            SM -= excess;
            float evapfactor = fminf(fmaxf(SM * invLPFC, 0.0f), 1.0f);
            float ETact = fminf(SM, ETp * evapfactor);
            SM = fmaxf(SM - ETact, PRECS_F);

            SUZ += recharge + excess;
            float PERC = fminf(SUZ, parPERC);
            SUZ -= PERC;
            float Q0 = parK0 * fmaxf(SUZ - parUZL, 0.0f);
            SUZ -= Q0;
            float Q1 = parK1 * SUZ;
            SUZ -= Q1;
            SLZ += PERC;
            float Q2 = parK2 * SLZ;
            SLZ -= Q2;

            const int t = t0 + j;
            if (t < NSTEP) out[(size_t)t * NGRID + g] = Q0 + Q1 + Q2;
        }
    };

    // Software pipeline: double-buffered register prefetch, unrolled x2 so
    // both buffers are indexed with compile-time constants (stay in VGPRs).
    load_chunk(0, AP, AT, AE);
    int c = 0;
    for (;;) {
        if (c + 1 < nchunks) load_chunk(c + 1, BP, BT, BE);
        compute_chunk(c, AP, AT, AE);
        if (++c >= nchunks) break;
        if (c + 1 < nchunks) load_chunk(c + 1, AP, AT, AE);
        compute_chunk(c, BP, BT, BE);
        if (++c >= nchunks) break;
    }
}

extern "C" void kernel_launch(void* const* d_in, const int* in_sizes, int n_in,
                              void* d_out, int out_size, void* d_ws, size_t ws_size,
                              hipStream_t stream) {
    const float* x      = (const float*)d_in[0];
    const float* params = (const float*)d_in[1];
    float* out          = (float*)d_out;

    const int block = 64;
    const int grid  = (NGRID + block - 1) / block;  // 782 blocks -> spread over 256 CUs
    hbv_kernel<<<grid, block, 0, stream>>>(x, params, out);
}